// Round 13
// baseline (105.044 us; speedup 1.0000x reference)
//
#include <hip/hip_runtime.h>
#include <hip/hip_fp16.h>

// Seesaw_Conv: 3x3 conv (16->128) offsets -> scrambled bilinear sampling -> 9-tap weighted sum + residual
// B=4, C=16, H=W=192, K=3, KE=9, M=4
// ws layout: [0,73728): Wpack (f16 hi/lo B-fragments); [73728,+75497472): off2 float2[64][4][192][192]
// Sampler: f16 image in LDS (row stride 194), identity offset slots + register prefetch,
// 1 barrier/plane, __launch_bounds__(1024,1) so the 18-VGPR prefetch doesn't spill
// (LDS caps at 1 block/CU anyway -> 128-VGPR budget is free).
// Conv: MFMA implicit GEMM, exact f16 hi/lo split, 1-deep W-fragment prefetch pipeline.

#define HH 192
#define WW 192
#define CC 16
#define CO 128
#define IMG_N (HH * WW)
#define ISTR 194  // img LDS row stride in halves (97 dwords, odd -> bank-clean)
#define XSTR 10   // dwords per (row,col) cell in conv packed x-tile

typedef _Float16 f16x8 __attribute__((ext_vector_type(8)));
typedef float f32x4 __attribute__((ext_vector_type(4)));
typedef uint u32x4 __attribute__((ext_vector_type(4)));

static __device__ __forceinline__ f16x8 ld_frag_global(const uint* p) {
  u32x4 v = *(const u32x4*)p;
  return __builtin_bit_cast(f16x8, v);
}

// Prepack W into MFMA B-fragment order, f16 hi+lo. (validated)
__global__ __launch_bounds__(256) void prepack_w_kernel(
    const float* __restrict__ Wref, uint* __restrict__ Wpack) {
  int e = blockIdx.x * 256 + threadIdx.x;
  if (e >= 2304) return;
  int s, btg, l;
  if (e < 2048) { s = e >> 9; int rem = e & 511; btg = rem >> 6; l = rem & 63; }
  else { s = 4; int rem = e - 2048; btg = rem >> 5; l = rem & 31; }
  int g = l >> 4;
  int tap = s * 2 + (g >> 1);
  int co = btg * 16 + (l & 15);
  int cin0 = (g & 1) * 8;
  int kh = (tap * 11) >> 5;
  int kw = tap - 3 * kh;
  uint hd[4], ld[4];
  #pragma unroll
  for (int j = 0; j < 4; ++j) {
    uint hh[2], ll[2];
    #pragma unroll
    for (int q = 0; q < 2; ++q) {
      int i = 2 * j + q;
      float v = Wref[((co * CC + cin0 + i) * 3 + kh) * 3 + kw];
      __half h = __float2half(v);
      __half lo = __float2half(v - __half2float(h));
      hh[q] = __half_as_ushort(h);
      ll[q] = __half_as_ushort(lo);
    }
    hd[j] = hh[0] | (hh[1] << 16);
    ld[j] = ll[0] | (ll[1] << 16);
  }
  uint base = (e < 2048) ? (uint)e * 8u : 16384u + (uint)(btg * 32 + l) * 8u;
  #pragma unroll
  for (int j = 0; j < 4; ++j) { Wpack[base + j] = hd[j]; Wpack[base + 4 + j] = ld[j]; }
}

struct WF { f16x8 bh0, bl0, bh1, bl1; };

static __device__ __forceinline__ WF load_w(const uint* __restrict__ Wpack,
                                            int s, int btg0, int l) {
  WF f;
  u32x4 z4 = {0, 0, 0, 0};
  f.bh0 = __builtin_bit_cast(f16x8, z4);
  f.bl0 = f.bh0; f.bh1 = f.bh0; f.bl1 = f.bh0;
  if (s < 4) {
    const uint* bp0 = Wpack + (size_t)((s * 8 + btg0) * 64 + l) * 8;
    f.bh0 = ld_frag_global(bp0);
    f.bl0 = ld_frag_global(bp0 + 4);
    const uint* bp1 = Wpack + (size_t)((s * 8 + btg0 + 1) * 64 + l) * 8;
    f.bh1 = ld_frag_global(bp1);
    f.bl1 = ld_frag_global(bp1 + 4);
  } else if (l < 32) {
    const uint* bp0 = Wpack + 16384 + (size_t)(btg0 * 32 + l) * 8;
    f.bh0 = ld_frag_global(bp0);
    f.bl0 = ld_frag_global(bp0 + 4);
    const uint* bp1 = Wpack + 16384 + (size_t)((btg0 + 1) * 32 + l) * 8;
    f.bh1 = ld_frag_global(bp1);
    f.bl1 = ld_frag_global(bp1 + 4);
  }
  return f;
}

// MFMA conv. Block: 2 rows x 64 w x 64 co, 256 thr = 4 waves; W-frag 1-deep prefetch.
__global__ __launch_bounds__(256, 2) void conv_kernel(
    const float* __restrict__ x, const uint* __restrict__ Wpack,
    const float* __restrict__ bref, float2* __restrict__ off2) {
  __shared__ uint smem[2 * 2640];  // XH | XL (21120 B); epilogue reuse: float sb[128*33]
  uint* XH = smem;
  uint* XL = smem + 2640;
  int bid = blockIdx.x;
  int cblk = bid & 1;
  int wt_ = (bid >> 1) % 3;
  int hp = (bid / 6) % 96;
  int b = bid / 576;
  int w0 = wt_ * 64, h0 = hp * 2;
  int t = threadIdx.x;
  int l = t & 63, wv = t >> 6;
  int r = wv & 1, wn = wv >> 1;
  int g = l >> 4, l15 = l & 15;
  int btg0 = cblk * 4 + wn * 2;

  WF cur = load_w(Wpack, 0, btg0, l);  // overlaps with x staging below

  for (int idx = t; idx < 2112; idx += 256) {
    int cp = idx / 264;
    int rem = idx - cp * 264;
    int row = rem / 66;
    int col = rem - row * 66;
    int gh = h0 + row - 1, gw = w0 + col - 1;
    float v0 = 0.0f, v1 = 0.0f;
    if ((unsigned)gh < 192u && (unsigned)gw < 192u) {
      const float* gp = x + ((size_t)(b * CC + 2 * cp) * HH + gh) * WW + gw;
      v0 = gp[0];
      v1 = gp[IMG_N];
    }
    __half ha = __float2half(v0), hb = __float2half(v1);
    __half la = __float2half(v0 - __half2float(ha));
    __half lb = __float2half(v1 - __half2float(hb));
    int a = (row * 66 + col) * XSTR + cp;
    XH[a] = (uint)__half_as_ushort(ha) | ((uint)__half_as_ushort(hb) << 16);
    XL[a] = (uint)__half_as_ushort(la) | ((uint)__half_as_ushort(lb) << 16);
  }

  int base0 = (r * 66 + l15) * XSTR + (g & 1) * 4;
  int tapl = g >> 1;
  f32x4 acc[4][2];
  #pragma unroll
  for (int af = 0; af < 4; ++af)
    #pragma unroll
    for (int bt = 0; bt < 2; ++bt) acc[af][bt] = (f32x4){0.f, 0.f, 0.f, 0.f};

  __syncthreads();

  #pragma unroll 1
  for (int s = 0; s < 5; ++s) {
    WF nxt = cur;
    if (s < 4) nxt = load_w(Wpack, s + 1, btg0, l);  // issue early; waits land next iter
    int tap = s * 2 + tapl;
    if (tap > 8) tap = 8;
    int kh = (tap * 11) >> 5;
    int kw = tap - 3 * kh;
    int delta = (kh * 66 + kw) * XSTR;
    #pragma unroll
    for (int af = 0; af < 4; ++af) {
      int ap = base0 + af * (16 * XSTR) + delta;
      uint2 h01 = *(const uint2*)&XH[ap];
      uint2 h23 = *(const uint2*)&XH[ap + 2];
      uint2 l01 = *(const uint2*)&XL[ap];
      uint2 l23 = *(const uint2*)&XL[ap + 2];
      u32x4 th = {h01.x, h01.y, h23.x, h23.y};
      u32x4 tl = {l01.x, l01.y, l23.x, l23.y};
      f16x8 ah = __builtin_bit_cast(f16x8, th);
      f16x8 al = __builtin_bit_cast(f16x8, tl);
      acc[af][0] = __builtin_amdgcn_mfma_f32_16x16x32_f16(ah, cur.bh0, acc[af][0], 0, 0, 0);
      acc[af][0] = __builtin_amdgcn_mfma_f32_16x16x32_f16(ah, cur.bl0, acc[af][0], 0, 0, 0);
      acc[af][0] = __builtin_amdgcn_mfma_f32_16x16x32_f16(al, cur.bh0, acc[af][0], 0, 0, 0);
      acc[af][1] = __builtin_amdgcn_mfma_f32_16x16x32_f16(ah, cur.bh1, acc[af][1], 0, 0, 0);
      acc[af][1] = __builtin_amdgcn_mfma_f32_16x16x32_f16(ah, cur.bl1, acc[af][1], 0, 0, 0);
      acc[af][1] = __builtin_amdgcn_mfma_f32_16x16x32_f16(al, cur.bh1, acc[af][1], 0, 0, 0);
    }
    cur = nxt;
  }

  float bias[2];
  #pragma unroll
  for (int bt = 0; bt < 2; ++bt) bias[bt] = bref[cblk * 64 + wn * 32 + bt * 16 + l15];
  float* sb = (float*)smem;
  #pragma unroll 1
  for (int c = 0; c < 2; ++c) {
    __syncthreads();
    if (wn == c) {
      #pragma unroll
      for (int bt = 0; bt < 2; ++bt)
        #pragma unroll
        for (int af = 0; af < 4; ++af)
          #pragma unroll
          for (int reg = 0; reg < 4; ++reg) {
            int px = r * 64 + af * 16 + g * 4 + reg;
            sb[px * 33 + bt * 16 + l15] = acc[af][bt][reg] + bias[bt];
          }
    }
    __syncthreads();
    int p_l = t >> 4, pxg = t & 15;
    int pair = cblk * 32 + c * 16 + p_l;
    int rr = pxg >> 3;
    float2* gbase = off2 + ((size_t)(pair * 4 + b) * IMG_N) + (h0 + rr) * WW + w0 + (pxg & 7) * 8;
    #pragma unroll
    for (int e2 = 0; e2 < 4; ++e2) {
      int px = pxg * 8 + e2 * 2;
      float4 v = {sb[px * 33 + 2 * p_l], sb[px * 33 + 2 * p_l + 1],
                  sb[(px + 1) * 33 + 2 * p_l], sb[(px + 1) * 33 + 2 * p_l + 1]};
      *(float4*)(gbase + e2 * 2) = v;
    }
  }
}

// Plane processor: taps from padded-stride LDS img; offsets via identity slot
// (myoff = oslot + lane*9). ONE barrier per plane (double-buffered sbuf).
template <int MODE>  // 0 = normal (ke2<4), 1 = sym (ke2>4), 2 = center (ke2==4)
__device__ __forceinline__ void process_plane(
    int ke2, int c2, int b2, int q, int tid, int h2_0, int w2_0,
    const float* wt, const __half* img, const float2* myoff, float (*sbuf)[65],
    const float* __restrict__ x, const float* __restrict__ bws,
    float* __restrict__ out) {
  float acc = 0.0f;
  int h2 = h2_0, w2 = w2_0;
  #pragma unroll
  for (int k = 0; k < 9; ++k) {
    float ox = 0.0f, oy = 0.0f;
    if (MODE != 2) {
      float2 o = myoff[k];
      if (MODE == 1) { ox = 2.0f - o.x; oy = 2.0f - o.y; }
      else           { ox = o.x;        oy = o.y; }
    }
    float xn = ox + (float)h2 * (1.0f / 191.0f);
    float yn = oy + (float)w2 * (1.0f / 191.0f);
    float ix = xn * 96.0f + 95.5f;
    float iy = yn * 96.0f + 95.5f;
    bool in = (ix > -1.0f) && (ix < 192.0f) && (iy > -1.0f) && (iy < 192.0f);
    bool go = (MODE == 1) ? __any(in) : true;
    if (go) {
      float x0f = floorf(ix), y0f = floorf(iy);
      float fx = ix - x0f, fy = iy - y0f;
      int x0 = (int)x0f, y0 = (int)y0f;
      int x1 = x0 + 1, y1 = y0 + 1;
      bool xi0 = (unsigned)x0 < 192u, xi1 = (unsigned)x1 < 192u;
      bool yi0 = (unsigned)y0 < 192u, yi1 = (unsigned)y1 < 192u;
      int xc0 = min(max(x0, 0), 191), xc1 = min(max(x1, 0), 191);
      int yc0 = min(max(y0, 0), 191), yc1 = min(max(y1, 0), 191);
      float v00 = (yi0 && xi0) ? __half2float(img[yc0 * ISTR + xc0]) : 0.0f;
      float v01 = (yi0 && xi1) ? __half2float(img[yc0 * ISTR + xc1]) : 0.0f;
      float v10 = (yi1 && xi0) ? __half2float(img[yc1 * ISTR + xc0]) : 0.0f;
      float v11 = (yi1 && xi1) ? __half2float(img[yc1 * ISTR + xc1]) : 0.0f;
      float sv = v00 * (1.0f - fy) * (1.0f - fx) + v01 * (1.0f - fy) * fx
               + v10 * fy * (1.0f - fx) + v11 * fy * fx;
      acc += wt[k] * sv;
    }
    if (++w2 == 192) { w2 = 0; ++h2; }
  }
  sbuf[tid & 15][tid >> 4] = acc;
  __syncthreads();  // separates this buf's writes from reads; next plane's barrier
                    // separates these reads from this buf's reuse (2 planes later).
  int cr = tid >> 6, wl = tid & 63;
  int plane_idx = (c2 * 9 + ke2) * 4 + b2;
  int t16b = plane_idx * 256 + q * 64;
  int w0 = t16b % 192;
  int hb = t16b / 192;
  int h = hb % 192;
  int b = hb / 192;
  size_t addr = ((size_t)(b * 16 + cr) * 192 + h) * 192 + w0 + wl;
  out[addr] = sbuf[cr][wl] + bws[cr] + x[addr];
}

// Grid 256: block = (imgid, quarter q).
// LDS: img 74496 | offs 16 waves x 576 float2 = 73728 | sbuf 2x4160 -> 156544 B.
// min-waves=1: LDS caps at 1 block/CU, so the 128-VGPR budget costs nothing and
// keeps the 18-dword offset prefetch out of scratch (R12's spill regression).
__global__ __launch_bounds__(1024, 1) void sample_kernel(
    const float* __restrict__ x, const float2* __restrict__ off2,
    const float* __restrict__ Wws, const float* __restrict__ bws,
    float* __restrict__ out) {
  extern __shared__ char smem[];
  __half* img = (__half*)smem;                          // 74496 B
  float2* offs = (float2*)(smem + 74496);               // 73728 B (16 wave slots x 576)
  float (*sbuf0)[65] = (float(*)[65])(smem + 148224);   // 4160 B
  float (*sbuf1)[65] = (float(*)[65])(smem + 152384);   // 4160 B
  int ib = blockIdx.x, tid = threadIdx.x;
  int imgid = ib >> 2, q = ib & 3;
  int b2 = imgid & 3, c2 = imgid >> 2;
  int c = tid & 15;
  float wt[9];
  #pragma unroll
  for (int k = 0; k < 9; ++k) wt[k] = Wws[c * 9 + k];
  int lane = tid & 63, wv = tid >> 6;
  float2* oslot = offs + wv * 576;
  const float2* myoff = oslot + lane * 9;
  // prefetch m=0 offsets coalesced (overlaps image staging)
  const float2* gp0 = off2 + (size_t)((c2 * 4 + 0) * 4 + b2) * IMG_N + q * 9216 + wv * 576;
  float2 pre[9];
  #pragma unroll
  for (int k = 0; k < 9; ++k) pre[k] = gp0[k * 64 + lane];
  // stage image f32 -> f16, row stride 194 halves
  const float4* xs = (const float4*)(x + (size_t)(b2 * CC + c2) * IMG_N);
  #pragma unroll
  for (int j = 0; j < 9; ++j) {
    int i4 = j * 1024 + tid;
    float4 v = xs[i4];
    int y = i4 / 48, x0 = (i4 % 48) * 4;
    __half2* ip = (__half2*)(img + y * ISTR + x0);
    ip[0] = __floats2half2_rn(v.x, v.y);
    ip[1] = __floats2half2_rn(v.z, v.w);
  }
  __syncthreads();
  int p0 = q * 9216 + 9 * tid;
  int h2_0 = p0 / 192, w2_0 = p0 % 192;
  int pl = 0;
  #pragma unroll 1
  for (int m = 0; m < 4; ++m) {
    // identity copy into wave-private slot (same-wave DS ordering: no barrier needed),
    // then prefetch m+1 into registers
    #pragma unroll
    for (int k = 0; k < 9; ++k) oslot[k * 64 + lane] = pre[k];
    if (m < 3) {
      const float2* gp = off2 + (size_t)((c2 * 4 + m + 1) * 4 + b2) * IMG_N + q * 9216 + wv * 576;
      #pragma unroll
      for (int k = 0; k < 9; ++k) pre[k] = gp[k * 64 + lane];
    }
    process_plane<0>(m, c2, b2, q, tid, h2_0, w2_0, wt, img, myoff,
                     (pl & 1) ? sbuf1 : sbuf0, x, bws, out);
    ++pl;
    process_plane<1>(m + 5, c2, b2, q, tid, h2_0, w2_0, wt, img, myoff,
                     (pl & 1) ? sbuf1 : sbuf0, x, bws, out);
    ++pl;
  }
  process_plane<2>(4, c2, b2, q, tid, h2_0, w2_0, wt, img, (const float2*)nullptr,
                   (pl & 1) ? sbuf1 : sbuf0, x, bws, out);
}

extern "C" void kernel_launch(void* const* d_in, const int* in_sizes, int n_in,
                              void* d_out, int out_size, void* d_ws, size_t ws_size,
                              hipStream_t stream) {
  (void)in_sizes; (void)n_in; (void)out_size; (void)ws_size;
  const float* x    = (const float*)d_in[0];
  const float* Wref = (const float*)d_in[1];
  const float* bref = (const float*)d_in[2];
  const float* Wws  = (const float*)d_in[3];
  const float* bws  = (const float*)d_in[4];
  float* out = (float*)d_out;
  uint* Wpack = (uint*)d_ws;                           // 73728 B
  float2* off2 = (float2*)((char*)d_ws + 73728);       // 75497472 B

  hipFuncSetAttribute(reinterpret_cast<const void*>(sample_kernel),
                      hipFuncAttributeMaxDynamicSharedMemorySize, 156544);
  prepack_w_kernel<<<9, 256, 0, stream>>>(Wref, Wpack);
  conv_kernel<<<2304, 256, 0, stream>>>(x, Wpack, bref, off2);
  sample_kernel<<<256, 1024, 156544, stream>>>(x, off2, Wws, bws, out);
}

// Round 14
// 95.428 us; speedup vs baseline: 1.1008x; 1.1008x over previous
//
#include <hip/hip_runtime.h>
#include <hip/hip_fp16.h>

// Seesaw_Conv: 3x3 conv (16->128) offsets -> scrambled bilinear sampling -> 9-tap weighted sum + residual
// B=4, C=16, H=W=192, K=3, KE=9, M=4
// ws layout: [0,73728): Wpack (f16 hi/lo B-fragments); [73728,+75497472): off2 float2[64][4][192][192]
// Sampler V2: per plane, thread (wv,lane) handles samples p = q*9216+wv*576+k*64+lane
// -> offset loads are directly coalesced (no LDS staging, no register carry), products
// regrouped via swizzled LDS pbuf (phys = s + s/144, stride-145 reads), double-buffered.
// Conv: MFMA implicit GEMM, exact f16 hi/lo split, 1-deep W-fragment prefetch (R13).

#define HH 192
#define WW 192
#define CC 16
#define CO 128
#define IMG_N (HH * WW)
#define ISTR 194  // img LDS row stride in halves (97 dwords, odd -> bank-clean)
#define XSTR 10   // dwords per (row,col) cell in conv packed x-tile

typedef _Float16 f16x8 __attribute__((ext_vector_type(8)));
typedef float f32x4 __attribute__((ext_vector_type(4)));
typedef uint u32x4 __attribute__((ext_vector_type(4)));

static __device__ __forceinline__ f16x8 ld_frag_global(const uint* p) {
  u32x4 v = *(const u32x4*)p;
  return __builtin_bit_cast(f16x8, v);
}

// Prepack W into MFMA B-fragment order, f16 hi+lo. (validated)
__global__ __launch_bounds__(256) void prepack_w_kernel(
    const float* __restrict__ Wref, uint* __restrict__ Wpack) {
  int e = blockIdx.x * 256 + threadIdx.x;
  if (e >= 2304) return;
  int s, btg, l;
  if (e < 2048) { s = e >> 9; int rem = e & 511; btg = rem >> 6; l = rem & 63; }
  else { s = 4; int rem = e - 2048; btg = rem >> 5; l = rem & 31; }
  int g = l >> 4;
  int tap = s * 2 + (g >> 1);
  int co = btg * 16 + (l & 15);
  int cin0 = (g & 1) * 8;
  int kh = (tap * 11) >> 5;
  int kw = tap - 3 * kh;
  uint hd[4], ld[4];
  #pragma unroll
  for (int j = 0; j < 4; ++j) {
    uint hh[2], ll[2];
    #pragma unroll
    for (int q = 0; q < 2; ++q) {
      int i = 2 * j + q;
      float v = Wref[((co * CC + cin0 + i) * 3 + kh) * 3 + kw];
      __half h = __float2half(v);
      __half lo = __float2half(v - __half2float(h));
      hh[q] = __half_as_ushort(h);
      ll[q] = __half_as_ushort(lo);
    }
    hd[j] = hh[0] | (hh[1] << 16);
    ld[j] = ll[0] | (ll[1] << 16);
  }
  uint base = (e < 2048) ? (uint)e * 8u : 16384u + (uint)(btg * 32 + l) * 8u;
  #pragma unroll
  for (int j = 0; j < 4; ++j) { Wpack[base + j] = hd[j]; Wpack[base + 4 + j] = ld[j]; }
}

struct WF { f16x8 bh0, bl0, bh1, bl1; };

static __device__ __forceinline__ WF load_w(const uint* __restrict__ Wpack,
                                            int s, int btg0, int l) {
  WF f;
  u32x4 z4 = {0, 0, 0, 0};
  f.bh0 = __builtin_bit_cast(f16x8, z4);
  f.bl0 = f.bh0; f.bh1 = f.bh0; f.bl1 = f.bh0;
  if (s < 4) {
    const uint* bp0 = Wpack + (size_t)((s * 8 + btg0) * 64 + l) * 8;
    f.bh0 = ld_frag_global(bp0);
    f.bl0 = ld_frag_global(bp0 + 4);
    const uint* bp1 = Wpack + (size_t)((s * 8 + btg0 + 1) * 64 + l) * 8;
    f.bh1 = ld_frag_global(bp1);
    f.bl1 = ld_frag_global(bp1 + 4);
  } else if (l < 32) {
    const uint* bp0 = Wpack + 16384 + (size_t)(btg0 * 32 + l) * 8;
    f.bh0 = ld_frag_global(bp0);
    f.bl0 = ld_frag_global(bp0 + 4);
    const uint* bp1 = Wpack + 16384 + (size_t)((btg0 + 1) * 32 + l) * 8;
    f.bh1 = ld_frag_global(bp1);
    f.bl1 = ld_frag_global(bp1 + 4);
  }
  return f;
}

// MFMA conv. Block: 2 rows x 64 w x 64 co, 256 thr = 4 waves; W-frag 1-deep prefetch.
__global__ __launch_bounds__(256, 2) void conv_kernel(
    const float* __restrict__ x, const uint* __restrict__ Wpack,
    const float* __restrict__ bref, float2* __restrict__ off2) {
  __shared__ uint smem[2 * 2640];  // XH | XL (21120 B); epilogue reuse: float sb[128*33]
  uint* XH = smem;
  uint* XL = smem + 2640;
  int bid = blockIdx.x;
  int cblk = bid & 1;
  int wt_ = (bid >> 1) % 3;
  int hp = (bid / 6) % 96;
  int b = bid / 576;
  int w0 = wt_ * 64, h0 = hp * 2;
  int t = threadIdx.x;
  int l = t & 63, wv = t >> 6;
  int r = wv & 1, wn = wv >> 1;
  int g = l >> 4, l15 = l & 15;
  int btg0 = cblk * 4 + wn * 2;

  WF cur = load_w(Wpack, 0, btg0, l);  // overlaps with x staging below

  for (int idx = t; idx < 2112; idx += 256) {
    int cp = idx / 264;
    int rem = idx - cp * 264;
    int row = rem / 66;
    int col = rem - row * 66;
    int gh = h0 + row - 1, gw = w0 + col - 1;
    float v0 = 0.0f, v1 = 0.0f;
    if ((unsigned)gh < 192u && (unsigned)gw < 192u) {
      const float* gp = x + ((size_t)(b * CC + 2 * cp) * HH + gh) * WW + gw;
      v0 = gp[0];
      v1 = gp[IMG_N];
    }
    __half ha = __float2half(v0), hb = __float2half(v1);
    __half la = __float2half(v0 - __half2float(ha));
    __half lb = __float2half(v1 - __half2float(hb));
    int a = (row * 66 + col) * XSTR + cp;
    XH[a] = (uint)__half_as_ushort(ha) | ((uint)__half_as_ushort(hb) << 16);
    XL[a] = (uint)__half_as_ushort(la) | ((uint)__half_as_ushort(lb) << 16);
  }

  int base0 = (r * 66 + l15) * XSTR + (g & 1) * 4;
  int tapl = g >> 1;
  f32x4 acc[4][2];
  #pragma unroll
  for (int af = 0; af < 4; ++af)
    #pragma unroll
    for (int bt = 0; bt < 2; ++bt) acc[af][bt] = (f32x4){0.f, 0.f, 0.f, 0.f};

  __syncthreads();

  #pragma unroll 1
  for (int s = 0; s < 5; ++s) {
    WF nxt = cur;
    if (s < 4) nxt = load_w(Wpack, s + 1, btg0, l);  // issue early; waits land next iter
    int tap = s * 2 + tapl;
    if (tap > 8) tap = 8;
    int kh = (tap * 11) >> 5;
    int kw = tap - 3 * kh;
    int delta = (kh * 66 + kw) * XSTR;
    #pragma unroll
    for (int af = 0; af < 4; ++af) {
      int ap = base0 + af * (16 * XSTR) + delta;
      uint2 h01 = *(const uint2*)&XH[ap];
      uint2 h23 = *(const uint2*)&XH[ap + 2];
      uint2 l01 = *(const uint2*)&XL[ap];
      uint2 l23 = *(const uint2*)&XL[ap + 2];
      u32x4 th = {h01.x, h01.y, h23.x, h23.y};
      u32x4 tl = {l01.x, l01.y, l23.x, l23.y};
      f16x8 ah = __builtin_bit_cast(f16x8, th);
      f16x8 al = __builtin_bit_cast(f16x8, tl);
      acc[af][0] = __builtin_amdgcn_mfma_f32_16x16x32_f16(ah, cur.bh0, acc[af][0], 0, 0, 0);
      acc[af][0] = __builtin_amdgcn_mfma_f32_16x16x32_f16(ah, cur.bl0, acc[af][0], 0, 0, 0);
      acc[af][0] = __builtin_amdgcn_mfma_f32_16x16x32_f16(al, cur.bh0, acc[af][0], 0, 0, 0);
      acc[af][1] = __builtin_amdgcn_mfma_f32_16x16x32_f16(ah, cur.bh1, acc[af][1], 0, 0, 0);
      acc[af][1] = __builtin_amdgcn_mfma_f32_16x16x32_f16(ah, cur.bl1, acc[af][1], 0, 0, 0);
      acc[af][1] = __builtin_amdgcn_mfma_f32_16x16x32_f16(al, cur.bh1, acc[af][1], 0, 0, 0);
    }
    cur = nxt;
  }

  float bias[2];
  #pragma unroll
  for (int bt = 0; bt < 2; ++bt) bias[bt] = bref[cblk * 64 + wn * 32 + bt * 16 + l15];
  float* sb = (float*)smem;
  #pragma unroll 1
  for (int c = 0; c < 2; ++c) {
    __syncthreads();
    if (wn == c) {
      #pragma unroll
      for (int bt = 0; bt < 2; ++bt)
        #pragma unroll
        for (int af = 0; af < 4; ++af)
          #pragma unroll
          for (int reg = 0; reg < 4; ++reg) {
            int px = r * 64 + af * 16 + g * 4 + reg;
            sb[px * 33 + bt * 16 + l15] = acc[af][bt][reg] + bias[bt];
          }
    }
    __syncthreads();
    int p_l = t >> 4, pxg = t & 15;
    int pair = cblk * 32 + c * 16 + p_l;
    int rr = pxg >> 3;
    float2* gbase = off2 + ((size_t)(pair * 4 + b) * IMG_N) + (h0 + rr) * WW + w0 + (pxg & 7) * 8;
    #pragma unroll
    for (int e2 = 0; e2 < 4; ++e2) {
      int px = pxg * 8 + e2 * 2;
      float4 v = {sb[px * 33 + 2 * p_l], sb[px * 33 + 2 * p_l + 1],
                  sb[(px + 1) * 33 + 2 * p_l], sb[(px + 1) * 33 + 2 * p_l + 1]};
      *(float4*)(gbase + e2 * 2) = v;
    }
  }
}

// Sampler V2 plane processor. Thread (wv,lane) handles samples p_rel = wv*576+k*64+lane
// (k=0..8): coalesced direct global offset load, tap from LDS img, product into swizzled
// pbuf. Then regroup: thread (wv=c, lane=w_hi) sums 9 products of output w_hi*16+c.
template <int MODE>  // 0 = normal (ke2<4), 1 = sym (ke2>4), 2 = center (ke2==4)
__device__ __forceinline__ void plane_v2(
    int ke2, int c2, int b2, int q, int wv, int lane,
    const float* wk, const __half* img, const float2* __restrict__ ob,
    float* pb, const float* __restrict__ x, const float* __restrict__ bws,
    float* __restrict__ out) {
  int p_base = wv * 576 + lane;
  int h2b = q * 48 + wv * 3;
  #pragma unroll 3
  for (int k = 0; k < 9; ++k) {
    int p_rel = p_base + k * 64;
    float ox = 0.0f, oy = 0.0f;
    if (MODE != 2) {
      float2 o = ob[p_rel];            // coalesced: 64 consecutive float2 per (wv,k)
      if (MODE == 1) { ox = 2.0f - o.x; oy = 2.0f - o.y; }
      else           { ox = o.x;        oy = o.y; }
    }
    int h2 = h2b + k / 3;
    int w2 = (k % 3) * 64 + lane;
    float xn = ox + (float)h2 * (1.0f / 191.0f);
    float yn = oy + (float)w2 * (1.0f / 191.0f);
    float ix = xn * 96.0f + 95.5f;
    float iy = yn * 96.0f + 95.5f;
    float prod = 0.0f;
    bool in = (ix > -1.0f) && (ix < 192.0f) && (iy > -1.0f) && (iy < 192.0f);
    bool go = (MODE == 1) ? __any(in) : true;  // sym planes mostly OOB -> wave skip
    if (go) {
      float x0f = floorf(ix), y0f = floorf(iy);
      float fx = ix - x0f, fy = iy - y0f;
      int x0 = (int)x0f, y0 = (int)y0f;
      int x1 = x0 + 1, y1 = y0 + 1;
      bool xi0 = (unsigned)x0 < 192u, xi1 = (unsigned)x1 < 192u;
      bool yi0 = (unsigned)y0 < 192u, yi1 = (unsigned)y1 < 192u;
      int xc0 = min(max(x0, 0), 191), xc1 = min(max(x1, 0), 191);
      int yc0 = min(max(y0, 0), 191), yc1 = min(max(y1, 0), 191);
      float v00 = (yi0 && xi0) ? __half2float(img[yc0 * ISTR + xc0]) : 0.0f;
      float v01 = (yi0 && xi1) ? __half2float(img[yc0 * ISTR + xc1]) : 0.0f;
      float v10 = (yi1 && xi0) ? __half2float(img[yc1 * ISTR + xc0]) : 0.0f;
      float v11 = (yi1 && xi1) ? __half2float(img[yc1 * ISTR + xc1]) : 0.0f;
      float sv = v00 * (1.0f - fy) * (1.0f - fx) + v01 * (1.0f - fy) * fx
               + v10 * fy * (1.0f - fx) + v11 * fy * fx;
      prod = wk[k] * sv;
    }
    pb[p_rel + p_rel / 144] = prod;    // swizzle: phys = s + s/144
  }
  __syncthreads();  // writers done; (buffer-reuse hazard covered by dbuf + next barrier)
  // reader: c = wv, w_hi = lane; output o_rel = w_hi*16 + c; phys base = 145*w_hi + 9*c
  int c = wv, w_hi = lane;
  float sum = 0.0f;
  int pbase = 145 * w_hi + 9 * c;      // stride 145 across lanes -> conflict-free
  #pragma unroll
  for (int j = 0; j < 9; ++j) sum += pb[pbase + j];
  int plane_idx = (c2 * 9 + ke2) * 4 + b2;
  int t16b = plane_idx * 256 + q * 64;
  int w0 = t16b % 192;
  int hb = t16b / 192;
  int h = hb % 192;
  int b = hb / 192;
  size_t addr = ((size_t)(b * 16 + c) * 192 + h) * 192 + w0 + w_hi;
  out[addr] = sum + bws[c] + x[addr];
}

// Grid 256: block = (imgid, quarter q).
// LDS: img 74496 | pbuf0 37120 | pbuf1 37120 = 148736 B. 1024 threads, no reg carry
// across plane calls (the R12/R13 spill lesson: 1024-thr blocks cap at 64 VGPRs).
__global__ __launch_bounds__(1024) void sample_kernel(
    const float* __restrict__ x, const float2* __restrict__ off2,
    const float* __restrict__ Wws, const float* __restrict__ bws,
    float* __restrict__ out) {
  extern __shared__ char smem[];
  __half* img = (__half*)smem;                    // 74496 B
  float* pbuf0 = (float*)(smem + 74496);          // 37120 B (9280 floats)
  float* pbuf1 = (float*)(smem + 111616);         // 37120 B
  int ib = blockIdx.x, tid = threadIdx.x;
  int imgid = ib >> 2, q = ib & 3;
  int b2 = imgid & 3, c2 = imgid >> 2;
  int lane = tid & 63, wv = tid >> 6;
  // per-k tap weights: depend only on p (not m/plane) -> gather once
  float wk[9];
  {
    int pb0 = q * 9216 + wv * 576 + lane;
    #pragma unroll
    for (int k = 0; k < 9; ++k) {
      int p = pb0 + k * 64;
      int ke = p % 9;
      int c = (p / 9) % 16;
      wk[k] = Wws[c * 9 + ke];
    }
  }
  // stage image f32 -> f16, row stride 194 halves (validated)
  const float4* xs = (const float4*)(x + (size_t)(b2 * CC + c2) * IMG_N);
  #pragma unroll
  for (int j = 0; j < 9; ++j) {
    int i4 = j * 1024 + tid;
    float4 v = xs[i4];
    int y = i4 / 48, x0 = (i4 % 48) * 4;
    __half2* ip = (__half2*)(img + y * ISTR + x0);
    ip[0] = __floats2half2_rn(v.x, v.y);
    ip[1] = __floats2half2_rn(v.z, v.w);
  }
  __syncthreads();
  int pl = 0;
  #pragma unroll 1
  for (int m = 0; m < 4; ++m) {
    const float2* ob = off2 + (size_t)((c2 * 4 + m) * 4 + b2) * IMG_N + q * 9216;
    plane_v2<0>(m, c2, b2, q, wv, lane, wk, img, ob,
                (pl & 1) ? pbuf1 : pbuf0, x, bws, out);
    ++pl;
    plane_v2<1>(m + 5, c2, b2, q, wv, lane, wk, img, ob,
                (pl & 1) ? pbuf1 : pbuf0, x, bws, out);
    ++pl;
  }
  plane_v2<2>(4, c2, b2, q, wv, lane, wk, img, (const float2*)nullptr,
              (pl & 1) ? pbuf1 : pbuf0, x, bws, out);
}

extern "C" void kernel_launch(void* const* d_in, const int* in_sizes, int n_in,
                              void* d_out, int out_size, void* d_ws, size_t ws_size,
                              hipStream_t stream) {
  (void)in_sizes; (void)n_in; (void)out_size; (void)ws_size;
  const float* x    = (const float*)d_in[0];
  const float* Wref = (const float*)d_in[1];
  const float* bref = (const float*)d_in[2];
  const float* Wws  = (const float*)d_in[3];
  const float* bws  = (const float*)d_in[4];
  float* out = (float*)d_out;
  uint* Wpack = (uint*)d_ws;                           // 73728 B
  float2* off2 = (float2*)((char*)d_ws + 73728);       // 75497472 B

  hipFuncSetAttribute(reinterpret_cast<const void*>(sample_kernel),
                      hipFuncAttributeMaxDynamicSharedMemorySize, 148736);
  prepack_w_kernel<<<9, 256, 0, stream>>>(Wref, Wpack);
  conv_kernel<<<2304, 256, 0, stream>>>(x, Wpack, bref, off2);
  sample_kernel<<<256, 1024, 148736, stream>>>(x, off2, Wws, bws, out);
}